// Round 3
// baseline (5349.303 us; speedup 1.0000x reference)
//
#include <hip/hip_runtime.h>

#define IMG_W 128
#define IMG_HW 16384

static __device__ __forceinline__ float bf2f(unsigned short u){
    union { unsigned int i; float f; } x; x.i = ((unsigned int)u) << 16; return x.f;
}
static __device__ __forceinline__ unsigned short f2bf(float f){
    unsigned int i = __float_as_uint(f);
    i += 0x7FFFu + ((i >> 16) & 1u);
    return (unsigned short)(i >> 16);
}

// ---- V = Wv*x + bv (1x1 conv); store PIXEL-MAJOR bf16: Vt[b][pix][256c] ----
__global__ __launch_bounds__(256) void vconv_kernel(
    const float* __restrict__ x, const float* __restrict__ Wv,
    const float* __restrict__ bv, unsigned short* __restrict__ Vt)
{
    __shared__ float a_s[16 * 68];
    __shared__ float b_s[16 * 68];
    const int t = threadIdx.x;
    const int p0 = blockIdx.x * 64;
    const int m0 = blockIdx.y * 64;
    const int b  = blockIdx.z;
    const int tm = t & 15, tn = t >> 4;
    float acc[16];
#pragma unroll
    for (int i = 0; i < 16; ++i) acc[i] = 0.f;
    const float* xb = x + (size_t)b * 256 * IMG_HW;
    for (int kc = 0; kc < 16; ++kc) {
        const int k0 = kc * 16;
#pragma unroll
        for (int i = 0; i < 4; ++i) {
            int e = t + 256 * i;
            int kk = e & 15, mm = e >> 4;
            a_s[kk * 68 + mm] = Wv[(m0 + mm) * 256 + k0 + kk];
        }
#pragma unroll
        for (int i = 0; i < 4; ++i) {
            int e = t + 256 * i;
            int nn = e & 63, kk = e >> 6;
            b_s[kk * 68 + nn] = xb[(size_t)(k0 + kk) * IMG_HW + p0 + nn];
        }
        __syncthreads();
#pragma unroll
        for (int kk = 0; kk < 16; ++kk) {
            float4 a4 = *reinterpret_cast<const float4*>(&a_s[kk * 68 + tm * 4]);
            float4 b4 = *reinterpret_cast<const float4*>(&b_s[kk * 68 + tn * 4]);
            float av[4] = {a4.x, a4.y, a4.z, a4.w};
            float bw[4] = {b4.x, b4.y, b4.z, b4.w};
#pragma unroll
            for (int ii = 0; ii < 4; ++ii)
#pragma unroll
                for (int jj = 0; jj < 4; ++jj)
                    acc[ii * 4 + jj] = fmaf(av[ii], bw[jj], acc[ii * 4 + jj]);
        }
        __syncthreads();
    }
    float bias[4];
#pragma unroll
    for (int ii = 0; ii < 4; ++ii) bias[ii] = bv[m0 + tm * 4 + ii];
#pragma unroll
    for (int jj = 0; jj < 4; ++jj) {
        int pix = p0 + tn * 4 + jj;
        ushort4 u;
        u.x = f2bf(acc[0 * 4 + jj] + bias[0]);
        u.y = f2bf(acc[1 * 4 + jj] + bias[1]);
        u.z = f2bf(acc[2 * 4 + jj] + bias[2]);
        u.w = f2bf(acc[3 * 4 + jj] + bias[3]);
        *reinterpret_cast<ushort4*>(&Vt[((size_t)b * IMG_HW + pix) * 256 + m0 + tm * 4]) = u;
    }
}

// ---- Q/K convs (tile-local padding via masks) + BN + ReLU; store Qt/Kt[slot][pix][32c] f32 ----
__global__ __launch_bounds__(256) void qk_kernel(
    const float* __restrict__ x,
    const float* __restrict__ Wq, const float* __restrict__ bq,
    const float* __restrict__ q_s, const float* __restrict__ q_o,
    const float* __restrict__ q_m, const float* __restrict__ q_v,
    const float* __restrict__ Wk, const float* __restrict__ bk,
    const float* __restrict__ k_s, const float* __restrict__ k_o,
    const float* __restrict__ k_m, const float* __restrict__ k_v,
    float* __restrict__ Qt, float* __restrict__ Kt)
{
    __shared__ float xs[32 * 204];    // [c 32][r 3][col 68-pad], cols 0..65 valid
    __shared__ float wqs[32 * 97];
    __shared__ float wks[32 * 97];
    const int t = threadIdx.x;
    const int x0 = blockIdx.x * 64;
    const int y  = blockIdx.y;
    const int pass = blockIdx.z >> 3;
    const int b    = blockIdx.z & 7;
    const int c8 = t >> 3;
    const int g  = t & 7;

    float mL[8], mR[8], mT[8], mB[8];
#pragma unroll
    for (int j = 0; j < 8; ++j) {
        int px = x0 + g * 8 + j;
        bool left, right, top, bot;
        if (pass == 0) {
            left = (px & 31) == 0; right = (px & 31) == 31;
            top  = (y  & 31) == 0; bot   = (y  & 31) == 31;
        } else {
            bool yb  = (y  < 16) || (y  >= 112);
            bool xb2 = (px < 16) || (px >= 112);
            left  = (px == 0) || (px == 16) || (px == 112) || (!yb && (px == 48 || px == 80));
            right = (px == 15) || (px == 111) || (px == 127) || (!yb && (px == 47 || px == 79));
            top   = (y == 0) || (y == 16) || (y == 112) || (!xb2 && (y == 48 || y == 80));
            bot   = (y == 15) || (y == 111) || (y == 127) || (!xb2 && (y == 47 || y == 79));
        }
        mL[j] = left  ? 0.f : 1.f;
        mR[j] = right ? 0.f : 1.f;
        mT[j] = top   ? 0.f : 1.f;
        mB[j] = bot   ? 0.f : 1.f;
    }

    float accq[8], acck[8];
#pragma unroll
    for (int j = 0; j < 8; ++j) { accq[j] = 0.f; acck[j] = 0.f; }

    for (int cc = 0; cc < 8; ++cc) {
        __syncthreads();
        const int cb = cc * 32;
        for (int e = t; e < 6336; e += 256) {
            int c = e / 198;
            int rem = e - c * 198;
            int r = rem / 66;
            int col = rem - r * 66;
            int gy = y + r - 1;
            int gx = x0 + col - 1;
            float v = 0.f;
            if (((unsigned)gy < 128u) && ((unsigned)gx < 128u))
                v = x[((size_t)(b * 256 + cb + c)) * IMG_HW + gy * IMG_W + gx];
            xs[c * 204 + r * 68 + col] = v;
        }
#pragma unroll
        for (int i = 0; i < 12; ++i) {
            int e = t + 256 * i;
            int ci = e / 96;
            int rem = e - ci * 96;
            wqs[ci * 97 + rem] = Wq[ci * 768 + cb * 3 + rem];
            wks[ci * 97 + rem] = Wk[ci * 768 + cb * 3 + rem];
        }
        __syncthreads();
        for (int c = 0; c < 32; ++c) {
            const float* xr = &xs[c * 204];
            float4 f0 = *reinterpret_cast<const float4*>(&xr[68 + g * 8]);
            float4 f1 = *reinterpret_cast<const float4*>(&xr[68 + g * 8 + 4]);
            float4 f2 = *reinterpret_cast<const float4*>(&xr[68 + g * 8 + 8]);
            float xm[12] = {f0.x,f0.y,f0.z,f0.w, f1.x,f1.y,f1.z,f1.w, f2.x,f2.y,f2.z,f2.w};
            float4 t0 = *reinterpret_cast<const float4*>(&xr[g * 8]);
            float4 t1 = *reinterpret_cast<const float4*>(&xr[g * 8 + 4]);
            float4 t2 = *reinterpret_cast<const float4*>(&xr[g * 8 + 8]);
            float xt[12] = {t0.x,t0.y,t0.z,t0.w, t1.x,t1.y,t1.z,t1.w, t2.x,t2.y,t2.z,t2.w};
            float4 u0 = *reinterpret_cast<const float4*>(&xr[136 + g * 8]);
            float4 u1 = *reinterpret_cast<const float4*>(&xr[136 + g * 8 + 4]);
            float4 u2 = *reinterpret_cast<const float4*>(&xr[136 + g * 8 + 8]);
            float xb_[12] = {u0.x,u0.y,u0.z,u0.w, u1.x,u1.y,u1.z,u1.w, u2.x,u2.y,u2.z,u2.w};
            float wq0 = wqs[c8 * 97 + c * 3 + 0];
            float wq1 = wqs[c8 * 97 + c * 3 + 1];
            float wq2 = wqs[c8 * 97 + c * 3 + 2];
            float wk0 = wks[c8 * 97 + c * 3 + 0];
            float wk1 = wks[c8 * 97 + c * 3 + 1];
            float wk2 = wks[c8 * 97 + c * 3 + 2];
#pragma unroll
            for (int j = 0; j < 8; ++j) {
                accq[j] = fmaf(wq0, xm[j] * mL[j], accq[j]);
                accq[j] = fmaf(wq1, xm[j + 1], accq[j]);
                accq[j] = fmaf(wq2, xm[j + 2] * mR[j], accq[j]);
                acck[j] = fmaf(wk0, xt[j + 1] * mT[j], acck[j]);
                acck[j] = fmaf(wk1, xm[j + 1], acck[j]);
                acck[j] = fmaf(wk2, xb_[j + 1] * mB[j], acck[j]);
            }
        }
    }
    float sq = q_s[c8] * rsqrtf(q_v[c8] + 1e-5f);
    float oq = q_o[c8] - q_m[c8] * sq;
    float sk = k_s[c8] * rsqrtf(k_v[c8] + 1e-5f);
    float ok = k_o[c8] - k_m[c8] * sk;
    float bqv = bq[c8], bkv = bk[c8];
    __syncthreads();
    float* qos = xs;               // [32c][66px]
    float* kos = xs + 32 * 66;
#pragma unroll
    for (int j = 0; j < 8; ++j) {
        qos[c8 * 66 + g * 8 + j] = fmaxf(0.f, fmaf(accq[j] + bqv, sq, oq));
        kos[c8 * 66 + g * 8 + j] = fmaxf(0.f, fmaf(acck[j] + bkv, sk, ok));
    }
    __syncthreads();
    const int pixb = (pass * 8 + b) * IMG_HW + y * IMG_W + x0;
#pragma unroll
    for (int i = 0; i < 8; ++i) {
        int e = t + 256 * i;        // 2048 = 64 px * 32 c
        int px = e >> 5, c = e & 31;
        Qt[(size_t)(pixb + px) * 32 + c] = qos[c * 66 + px];
        Kt[(size_t)(pixb + px) * 32 + c] = kos[c * 66 + px];
    }
}

// ---- out = x (identity base; both attn passes then accumulate 0.5*gamma*PV) ----
__global__ __launch_bounds__(256) void copy_kernel(const float* __restrict__ x, float* __restrict__ out)
{
    size_t idx = (size_t)blockIdx.x * 256 + threadIdx.x;
    const float4* x4 = reinterpret_cast<const float4*>(x);
    float4* o4 = reinterpret_cast<float4*>(out);
#pragma unroll
    for (int k = 0; k < 16; ++k)
        o4[idx + (size_t)k * 524288] = x4[idx + (size_t)k * 524288];
}

// ---- flash attention over a tile; adds 0.5*gamma*(V soft(QK^T)) into out ----
__global__ __launch_bounds__(256) void attn_kernel(
    const float* __restrict__ Qt, const float* __restrict__ Kt,
    const unsigned short* __restrict__ Vt, const float* __restrict__ gammap,
    float* __restrict__ out, int pass)
{
    __shared__ float smem[8480];   // 33,920 B
    float* k_sm  = smem;           // [32m][36]  main loop   [0,1152)
    float* s_sm  = smem + 1152;    // [64n][33]              [1152,3264)
    float* p_sm  = smem + 3264;    // [64n][36]              [3264,5568)
    float* o2_sm = smem;           // [32n][260] epilogue    [0,8320)
    float* r_sm  = smem + 8320;    // [64]
    float* l_sm  = smem + 8384;    // [64]
    int*  pix_sm = (int*)(smem + 8448); // [32]

    const int t = threadIdx.x;
    const int wv = t >> 6;
    const int lane = t & 63;
    const int bid = blockIdx.x;

    int y0, x0, h, w, b, nb;
    if (pass == 0) {                       // 12 tiles (y>=32) * 8 b * 16 nblk
        int tid = bid >> 7, r = bid & 127;
        b = r >> 4; nb = r & 15;
        y0 = 32 + 32 * (tid >> 2); x0 = 32 * (tid & 3); h = 32; w = 32;
    } else if (bid < 1152) {               // inner 3x3 tiles * 8 b * 16 nblk
        int tid = bid >> 7, r = bid & 127;
        b = r >> 4; nb = r & 15;
        y0 = 16 + 32 * (tid / 3); x0 = 16 + 32 * (tid % 3); h = 32; w = 32;
    } else if (bid < 1280) {               // 4 corners * 8 b * 4 nblk
        int q = bid - 1152;
        int ci = q >> 5, r = q & 31;
        b = r >> 2; nb = r & 3;
        y0 = (ci >> 1) * 112; x0 = (ci & 1) * 112; h = 16; w = 16;
    } else {                               // 4 edges * 8 b * 24 nblk
        int q = bid - 1280;
        int ei = q / 192, r = q - ei * 192;
        b = r / 24; nb = r - b * 24;
        h = (ei == 1 || ei == 2) ? 96 : 16;
        w = (h == 16) ? 96 : 16;
        y0 = (ei == 0) ? 0 : ((ei == 3) ? 112 : 16);
        x0 = (ei == 1) ? 0 : ((ei == 2) ? 112 : 16);
    }
    const int N = h * w;
    const int n0 = nb * 64;
    const int nmt = N >> 5;

    const int nS = n0 + lane;
    const int qy = nS / w;
    const int pixQ = (y0 + qy) * IMG_W + x0 + (nS - qy * w);
    const int qkb = (pass * 8 + b) * IMG_HW;

    float qreg[32];
    {
        const float* qp = &Qt[(size_t)(qkb + pixQ) * 32];
#pragma unroll
        for (int gg = 0; gg < 8; ++gg) {
            float4 q4 = *reinterpret_cast<const float4*>(qp + gg * 4);
            qreg[gg * 4 + 0] = q4.x; qreg[gg * 4 + 1] = q4.y;
            qreg[gg * 4 + 2] = q4.z; qreg[gg * 4 + 3] = q4.w;
        }
    }

    const int srow = 16 * wv + (lane & 15);
    const int mq = lane >> 4;
    float Mreg = -1e30f, Lreg = 0.f;
    float acc[64];
#pragma unroll
    for (int i = 0; i < 64; ++i) acc[i] = 0.f;

    const int cg = t & 7;      // staging: channel group
    const int mpix = t >> 3;   // staging: m index 0..31
    const size_t vb = (size_t)b * IMG_HW;

    for (int mt = 0; mt < nmt; ++mt) {
        {   // stage K tile [32m][32c] + pixel table
            int mIdx = mt * 32 + mpix;
            int my = mIdx / w;
            int pixM = (y0 + my) * IMG_W + x0 + (mIdx - my * w);
            float4 k4 = *reinterpret_cast<const float4*>(&Kt[(size_t)(qkb + pixM) * 32 + cg * 4]);
            *reinterpret_cast<float4*>(&k_sm[mpix * 36 + cg * 4]) = k4;
            if (cg == 0) pix_sm[mpix] = pixM;
        }
        __syncthreads();
        // S phase: thread (wv,lane) computes S[lane][8wv+j]
#pragma unroll
        for (int j = 0; j < 8; ++j) {
            int m = 8 * wv + j;
            const float* kr = &k_sm[m * 36];
            float s = 0.f;
#pragma unroll
            for (int gg = 0; gg < 8; ++gg) {
                float4 k4 = *reinterpret_cast<const float4*>(&kr[gg * 4]);
                s = fmaf(qreg[gg * 4 + 0], k4.x, s);
                s = fmaf(qreg[gg * 4 + 1], k4.y, s);
                s = fmaf(qreg[gg * 4 + 2], k4.z, s);
                s = fmaf(qreg[gg * 4 + 3], k4.w, s);
            }
            s_sm[lane * 33 + m] = s;
        }
        __syncthreads();
        // online softmax: row srow, 4 lanes (mq) each handle 8 m's
        float sv[8];
#pragma unroll
        for (int j = 0; j < 8; ++j) sv[j] = s_sm[srow * 33 + mq * 8 + j];
        float tmax = sv[0];
#pragma unroll
        for (int j = 1; j < 8; ++j) tmax = fmaxf(tmax, sv[j]);
        tmax = fmaxf(tmax, __shfl_xor(tmax, 16));
        tmax = fmaxf(tmax, __shfl_xor(tmax, 32));
        float newM = fmaxf(Mreg, tmax);
        float resc = __expf(Mreg - newM);
        float ps = 0.f;
#pragma unroll
        for (int j = 0; j < 8; ++j) {
            float pv = __expf(sv[j] - newM);
            ps += pv;
            p_sm[srow * 36 + mq * 8 + j] = pv;
        }
        ps += __shfl_xor(ps, 16);
        ps += __shfl_xor(ps, 32);
        Lreg = Lreg * resc + ps;
        Mreg = newM;
        if (mq == 0) r_sm[srow] = resc;
        __syncthreads();
        // rescale + PV (V read direct from global, pixel-major bf16)
#pragma unroll
        for (int i = 0; i < 16; ++i) {
            float rr = r_sm[16 * wv + i];
#pragma unroll
            for (int q2 = 0; q2 < 4; ++q2)
                acc[q2 * 16 + i] *= rr;
        }
#pragma unroll
        for (int mg = 0; mg < 8; ++mg) {
            float vm[4][4];
#pragma unroll
            for (int q2 = 0; q2 < 4; ++q2) {
                int pix = pix_sm[mg * 4 + q2];
                ushort4 u = *reinterpret_cast<const ushort4*>(&Vt[((size_t)(vb + pix)) * 256 + lane * 4]);
                vm[q2][0] = bf2f(u.x); vm[q2][1] = bf2f(u.y);
                vm[q2][2] = bf2f(u.z); vm[q2][3] = bf2f(u.w);
            }
#pragma unroll
            for (int i = 0; i < 16; ++i) {
                float4 p4 = *reinterpret_cast<const float4*>(&p_sm[(16 * wv + i) * 36 + mg * 4]);
                float pm[4] = {p4.x, p4.y, p4.z, p4.w};
#pragma unroll
                for (int jj = 0; jj < 4; ++jj) {
#pragma unroll
                    for (int q2 = 0; q2 < 4; ++q2)
                        acc[jj * 16 + i] = fmaf(vm[q2][jj], pm[q2], acc[jj * 16 + i]);
                }
            }
        }
        __syncthreads();
    }
    // epilogue: out += acc/l * 0.5*gamma, two 32-row halves through o2_sm
    if (mq == 0) l_sm[srow] = Lreg;
    __syncthreads();
    const float g2 = gammap[0] * 0.5f;
#pragma unroll
    for (int half = 0; half < 2; ++half) {
        if ((wv >> 1) == half) {
            int rl = (wv & 1) * 16;
#pragma unroll
            for (int i = 0; i < 16; ++i) {
                int n = 16 * wv + i;
                float f = g2 / l_sm[n];
                float4 o4;
                o4.x = acc[0 * 16 + i] * f;
                o4.y = acc[1 * 16 + i] * f;
                o4.z = acc[2 * 16 + i] * f;
                o4.w = acc[3 * 16 + i] * f;
                *reinterpret_cast<float4*>(&o2_sm[(rl + i) * 260 + lane * 4]) = o4;
            }
        }
        __syncthreads();
        {
            int nn = t & 31;
            int ng = n0 + half * 32 + nn;
            int ny = ng / w;
            int pixN = (y0 + ny) * IMG_W + x0 + (ng - ny * w);
#pragma unroll
            for (int i = 0; i < 32; ++i) {
                int c = (t >> 5) + 8 * i;
                size_t oi = ((size_t)(b * 256 + c)) * IMG_HW + pixN;
                out[oi] += o2_sm[nn * 260 + c];
            }
        }
        __syncthreads();
    }
}

extern "C" void kernel_launch(void* const* d_in, const int* in_sizes, int n_in,
                              void* d_out, int out_size, void* d_ws, size_t ws_size,
                              hipStream_t stream)
{
    (void)in_sizes; (void)n_in; (void)out_size;
    const float* x   = (const float*)d_in[0];
    const float* Wq  = (const float*)d_in[1];
    const float* bq  = (const float*)d_in[2];
    const float* q_s = (const float*)d_in[3];
    const float* q_o = (const float*)d_in[4];
    const float* q_m = (const float*)d_in[5];
    const float* q_v = (const float*)d_in[6];
    const float* Wk  = (const float*)d_in[7];
    const float* bk  = (const float*)d_in[8];
    const float* k_s = (const float*)d_in[9];
    const float* k_o = (const float*)d_in[10];
    const float* k_m = (const float*)d_in[11];
    const float* k_v = (const float*)d_in[12];
    const float* Wv  = (const float*)d_in[13];
    const float* bv  = (const float*)d_in[14];
    const float* gm  = (const float*)d_in[15];
    float* out = (float*)d_out;

    if (ws_size < (size_t)134217728) return;  // V(64MiB) + Q(32MiB) + K(32MiB)
    unsigned short* Vt = (unsigned short*)d_ws;
    float* Qt = (float*)((char*)d_ws + (size_t)67108864);
    float* Kt = (float*)((char*)d_ws + (size_t)100663296);

    vconv_kernel<<<dim3(256, 4, 8), dim3(256), 0, stream>>>(x, Wv, bv, Vt);
    qk_kernel<<<dim3(2, 128, 16), dim3(256), 0, stream>>>(
        x, Wq, bq, q_s, q_o, q_m, q_v, Wk, bk, k_s, k_o, k_m, k_v, Qt, Kt);
    copy_kernel<<<dim3(2048), dim3(256), 0, stream>>>(x, out);
    attn_kernel<<<dim3(1536), dim3(256), 0, stream>>>(Qt, Kt, Vt, gm, out, 0);
    attn_kernel<<<dim3(2048), dim3(256), 0, stream>>>(Qt, Kt, Vt, gm, out, 1);
}